// Round 4
// baseline (81.499 us; speedup 1.0000x reference)
//
#include <hip/hip_runtime.h>
#include <hip/hip_bf16.h>

// Collapsed GAT (all fp32): x is broadcast over nodes => softmax of a constant
// row is exactly uniform => both attention layers drop out:
//   wh[b,k,h]  = sum_f x[b,-1,f] * W_heads[k,f,h]
//   hp[b,k,h]  = elu(wh[b,k,h])
//   who[b,c]   = sum_{k,h} hp[b,k,h] * W_out[k*64+h, c]
//   out[b,c]   = bf[c] + sum_c2 who[b,c2] * WfSum[c,c2],  WfSum[c,c2]=sum_n Wf[c,n*64+c2]
//
// R4: kA = 384 blocks — 256 Wf-chunk blocks (row c × n-chunk of 128; 32 KB each,
// ~1.3 µs serial chain vs 5.3 µs for a full 128 KB row) writing 4 TRANSPOSED
// partial tiles, + 128 hp blocks (4 h-cols × all 32 batches each).
// kB = 32 blocks (per batch): who matvec (float4 W_out) + final 64x64 matvec
// summing the 4 WfSum partials on the fly + bias.
// ws layout: wsumT[chunk][c2*64+c] (4*16 KB) | HP[b*512+j] (64 KB)

__global__ __launch_bounds__(256) void kA(const float* __restrict__ Wf,
                                          const float* __restrict__ x,
                                          const float* __restrict__ W_heads,
                                          float* __restrict__ ws) {
    float* wsumT = ws;             // 4 * 64*64 partial tiles
    float* HP    = ws + 4 * 4096;  // 32*512
    const int t = threadIdx.x;

    if (blockIdx.x < 256) {
        // --- reduce chunk of row c of Wf (64 x 32768): n in [chunk*128, chunk*128+128) ---
        const int c     = blockIdx.x >> 2;   // 0..63
        const int chunk = blockIdx.x & 3;    // 0..3
        const float* row = Wf + (size_t)c * 32768 + chunk * 128 * 64;
        const int p  = t & 15;    // c2 quad
        const int ng = t >> 4;    // 0..15 n-group
        float ax = 0.f, ay = 0.f, az = 0.f, aw = 0.f;
#pragma unroll
        for (int i = 0; i < 8; ++i) {
            const float4 v = *reinterpret_cast<const float4*>(row + (ng + 16 * i) * 64 + p * 4);
            ax += v.x; ay += v.y; az += v.z; aw += v.w;
        }
        __shared__ float s[16][64];
        s[ng][p * 4 + 0] = ax; s[ng][p * 4 + 1] = ay;
        s[ng][p * 4 + 2] = az; s[ng][p * 4 + 3] = aw;
        __syncthreads();
        if (t < 64) {             // t = c2
            float sum = 0.f;
#pragma unroll
            for (int g = 0; g < 16; ++g) sum += s[g][t];
            wsumT[chunk * 4096 + t * 64 + c] = sum;   // transposed: [chunk][c2][c]
        }
    } else {
        // --- hp for 4 h-columns (one k), all 32 batches ---
        const int idx = blockIdx.x - 256;  // 0..127
        const int k  = idx >> 4;           // 0..7
        const int hq = (idx & 15) * 4;     // 0,4,...,60
        __shared__ float xl[32][129];      // +1 pad: breaks 16-way bank aliasing
#pragma unroll
        for (int r = 0; r < 4; ++r) {
            const int id = t + 256 * r;
            const int b = id >> 5, fq = id & 31;
            const float4 v = *reinterpret_cast<const float4*>(x + b * 1536 + 1408 + fq * 4);
            xl[b][fq * 4 + 0] = v.x; xl[b][fq * 4 + 1] = v.y;
            xl[b][fq * 4 + 2] = v.z; xl[b][fq * 4 + 3] = v.w;
        }
        __syncthreads();
        const int fh = t & 1;              // f half
        const int e  = (t >> 1) & 3;       // h within quad
        const int b  = t >> 3;             // 0..31
        const float* wp = W_heads + k * 8192 + fh * 4096 + hq + e;  // step f*64
        float acc = 0.f;
#pragma unroll 16
        for (int f = 0; f < 64; ++f)
            acc += xl[b][fh * 64 + f] * wp[f * 64];
        acc += __shfl_xor(acc, 1);         // combine the two f-halves
        if (fh == 0) {
            const float v = (acc > 0.f) ? acc : expm1f(acc);
            HP[b * 512 + k * 64 + hq + e] = v;
        }
    }
}

__global__ __launch_bounds__(256) void kB(const float* __restrict__ W_out,
                                          const float* __restrict__ bias,
                                          const float* __restrict__ ws,
                                          float* __restrict__ out) {
    const float* wsumT = ws;
    const float* HP    = ws + 4 * 4096;
    const int b = blockIdx.x;   // 0..31
    const int t = threadIdx.x;

    __shared__ float hp[512];
    __shared__ float s[16][64];
    __shared__ float who[64];
    __shared__ float red[256];

    hp[t]       = HP[b * 512 + t];
    hp[t + 256] = HP[b * 512 + 256 + t];
    __syncthreads();

    // who[c] = sum_j hp[j] * W_out[j,c] — 16-way j-parallel, float4 over c
    {
        const int cq = t & 15;    // c quad
        const int jg = t >> 4;    // 0..15
        float ax = 0.f, ay = 0.f, az = 0.f, aw = 0.f;
#pragma unroll 8
        for (int i = 0; i < 32; ++i) {
            const int j = jg + 16 * i;
            const float4 w = *reinterpret_cast<const float4*>(W_out + j * 64 + cq * 4);
            const float h = hp[j];
            ax += h * w.x; ay += h * w.y; az += h * w.z; aw += h * w.w;
        }
        s[jg][cq * 4 + 0] = ax; s[jg][cq * 4 + 1] = ay;
        s[jg][cq * 4 + 2] = az; s[jg][cq * 4 + 3] = aw;
    }
    __syncthreads();
    if (t < 64) {
        float sum = 0.f;
#pragma unroll
        for (int g = 0; g < 16; ++g) sum += s[g][t];
        who[t] = sum;
    }
    __syncthreads();

    // out[b,c] = bias[c] + sum_c2 who[c2] * (sum of 4 WfSumT partials)[c2][c]
    {
        const int c  = t & 63;
        const int cg = t >> 6;    // 0..3
        float acc = 0.f;
#pragma unroll
        for (int c2 = cg * 16; c2 < cg * 16 + 16; ++c2) {
            const int o = c2 * 64 + c;
            const float w = wsumT[o] + wsumT[4096 + o] + wsumT[8192 + o] + wsumT[12288 + o];
            acc += who[c2] * w;
        }
        red[t] = acc;
    }
    __syncthreads();
    if (t < 64)
        out[b * 64 + t] = red[t] + red[t + 64] + red[t + 128] + red[t + 192] + bias[t];
}

extern "C" void kernel_launch(void* const* d_in, const int* in_sizes, int n_in,
                              void* d_out, int out_size, void* d_ws, size_t ws_size,
                              hipStream_t stream) {
    const float* x       = (const float*)d_in[0]; // (32,12,128)
    const float* W_heads = (const float*)d_in[1]; // (8,128,64)
    // d_in[2], d_in[3]: a1_heads/a2_heads — unused (softmax of constant is uniform)
    const float* W_out   = (const float*)d_in[4]; // (512,64)
    // d_in[5], d_in[6]: a1_out/a2_out — unused
    const float* Wf      = (const float*)d_in[7]; // (64,32768)
    const float* bias    = (const float*)d_in[8]; // (64,)
    float* ws = (float*)d_ws;   // 64 KB wsumT partials + 64 KB HP

    kA<<<384, 256, 0, stream>>>(Wf, x, W_heads, ws);
    kB<<<32, 256, 0, stream>>>(W_out, bias, ws, (float*)d_out);
}